// Round 10
// baseline (78.205 us; speedup 1.0000x reference)
//
#include <hip/hip_runtime.h>

// feats [B=8, C=256, H=128, W=256] f32; labels [8,128,256] int32 in [0,19)
// out: means [19][256] then norm_means [19]  (4883 floats)
#define NCLS 19
#define NCH  256
#define HW   (128 * 256)          // 32768
#define NPIX (8 * HW)             // 262144
#define NGRP 4                    // channel groups (64 ch each)
#define GC   64                   // channels per group/block
#define P    256                  // pixels per tile -> 1-KB contiguous wave-loads
#define THP  260                  // bf16 tile row stride (520 B: b64 reads 2-way banks = free)
#define SQP  260                  // sqpart row stride (f32)
#define SUMS (NCLS * NCH)         // 4864
#define PN_CNT (SUMS + NCLS)      // 4883 outputs
#define GRID 512                  // = 128 pixel-chunks x 4 groups
#define PCHUNKS 128
#define CPX  (NPIX / PCHUNKS)     // 2048 px per chunk (contiguous, within one image)
#define TILES (CPX / P)           // 8
#define PST  1280                 // per-block partial stride (19*64=1216 padded)
#define NBLK 256                  // norm kernel blocks (1024 px each)
#define PNST 64                   // pnorm stride: [k]=norm, [32+k]=count
#define OFF_SQ ((size_t)GRID * PST)            // 655360 floats
#define OFF_PN (OFF_SQ + (size_t)NGRP * NPIX)  // +1048576

typedef __bf16 bf16x4v __attribute__((ext_vector_type(4)));
typedef __bf16 bf16x8v __attribute__((ext_vector_type(8)));
typedef float  f32x16v __attribute__((ext_vector_type(16)));
typedef int    int4v   __attribute__((ext_vector_type(4)));

// LDS-only barrier (no vmcnt drain): prefetch loads stay in flight.
__device__ __forceinline__ void bar_lds() {
    asm volatile("s_waitcnt lgkmcnt(0)" ::: "memory");
    __builtin_amdgcn_sched_barrier(0);
    __builtin_amdgcn_s_barrier();
    __builtin_amdgcn_sched_barrier(0);
}

__global__ __launch_bounds__(256, 3) void accum_kernel(
    const float* __restrict__ feats, const int* __restrict__ labels,
    float* __restrict__ ws)
{
    __shared__ __bf16 tileh[GC * THP];   // 33.3 KB  [c_local][px]
    __shared__ float  sqpart[4 * SQP];   // 4.2 KB   [wave][px] sq over 16 ch
    __shared__ int    lab_s[P];          // 1 KB
    __shared__ float  accf[32 * GC];     // 8 KB cross-wave accumulator merge

    const int t = threadIdx.x;
    const int g0 = blockIdx.x & 3, pchunk = blockIdx.x >> 2;
    const int pbase = pchunk * CPX;                 // chunk within one image
    const float* fb = feats + (size_t)(pbase >> 15) * NCH * HW
                            + (size_t)g0 * GC * HW + (pbase & (HW - 1));
    const int px4 = (t & 63) * 4;        // stage: lane covers 4 px; wave row = 1 KB
    const int wv  = t >> 6;              // wave id: stage channels wv+4i; K-pixels wv*64..
    const int l = t & 63, h = l >> 5, col = l & 31;

    for (int j = t; j < 32 * GC; j += 256) accf[j] = 0.f;

    f32x16v d0 = {}, d1 = {};            // [class 32][ch col], [class 32][ch col+32]
    float4 v4[16];
    int labv;

    // ---- prologue: load + stage tile 0 ----
    #pragma unroll
    for (int i = 0; i < 16; ++i)
        v4[i] = *reinterpret_cast<const float4*>(fb + (size_t)(wv + 4 * i) * HW + px4);
    labv = labels[pbase + t];
    {
        float s0 = 0.f, s1 = 0.f, s2 = 0.f, s3 = 0.f;
        #pragma unroll
        for (int i = 0; i < 16; ++i) {
            const int c = wv + 4 * i;
            bf16x4v hv = { (__bf16)v4[i].x, (__bf16)v4[i].y, (__bf16)v4[i].z, (__bf16)v4[i].w };
            *reinterpret_cast<bf16x4v*>(&tileh[c * THP + px4]) = hv;
            s0 += v4[i].x * v4[i].x; s1 += v4[i].y * v4[i].y;
            s2 += v4[i].z * v4[i].z; s3 += v4[i].w * v4[i].w;
        }
        sqpart[wv * SQP + px4    ] = s0; sqpart[wv * SQP + px4 + 1] = s1;
        sqpart[wv * SQP + px4 + 2] = s2; sqpart[wv * SQP + px4 + 3] = s3;
        lab_s[t] = labv;
    }
    __syncthreads();

    for (int it = 0; it < TILES; ++it) {
        // A: prefetch next tile (1-KB contiguous per wave-load; in flight across bar)
        if (it + 1 < TILES) {
            const int off = (it + 1) * P;
            #pragma unroll
            for (int i = 0; i < 16; ++i)
                v4[i] = *reinterpret_cast<const float4*>(fb + (size_t)(wv + 4 * i) * HW + off + px4);
            labv = labels[pbase + off + t];
        }
        // B: one-hot MFMA; wave wv owns K-pixels wv*64..wv*64+63 (4 K-steps)
        #pragma unroll
        for (int kk = 0; kk < 4; ++kk) {
            const int pb = wv * 64 + kk * 16 + h * 8;
            const int4v lq0 = *reinterpret_cast<const int4v*>(&lab_s[pb]);
            const int4v lq1 = *reinterpret_cast<const int4v*>(&lab_s[pb + 4]);
            const __bf16 ONE = (__bf16)1.0f, ZER = (__bf16)0.0f;
            bf16x8v af;
            af[0] = (lq0[0] == col) ? ONE : ZER;  af[1] = (lq0[1] == col) ? ONE : ZER;
            af[2] = (lq0[2] == col) ? ONE : ZER;  af[3] = (lq0[3] == col) ? ONE : ZER;
            af[4] = (lq1[0] == col) ? ONE : ZER;  af[5] = (lq1[1] == col) ? ONE : ZER;
            af[6] = (lq1[2] == col) ? ONE : ZER;  af[7] = (lq1[3] == col) ? ONE : ZER;
            const bf16x4v b0l = *reinterpret_cast<const bf16x4v*>(&tileh[col * THP + pb]);
            const bf16x4v b0h = *reinterpret_cast<const bf16x4v*>(&tileh[col * THP + pb + 4]);
            const bf16x4v b1l = *reinterpret_cast<const bf16x4v*>(&tileh[(col + 32) * THP + pb]);
            const bf16x4v b1h = *reinterpret_cast<const bf16x4v*>(&tileh[(col + 32) * THP + pb + 4]);
            const bf16x8v bf0 = __builtin_shufflevector(b0l, b0h, 0,1,2,3,4,5,6,7);
            const bf16x8v bf1 = __builtin_shufflevector(b1l, b1h, 0,1,2,3,4,5,6,7);
            d0 = __builtin_amdgcn_mfma_f32_32x32x16_bf16(af, bf0, d0, 0, 0, 0);
            d1 = __builtin_amdgcn_mfma_f32_32x32x16_bf16(af, bf1, d1, 0, 0, 0);
        }
        // C: per-pixel sq partial (this group's 64 ch) -> global; coalesced 1 KB/wave
        {
            const float sq = sqpart[t] + sqpart[SQP + t] + sqpart[2 * SQP + t] + sqpart[3 * SQP + t];
            ws[OFF_SQ + (size_t)g0 * NPIX + pbase + it * P + t] = sq;
        }
        bar_lds();   // LDS reads retired; prefetch loads NOT drained
        // D: stage prefetched tile (cvt/ds_write wait on own v4 regs only)
        if (it + 1 < TILES) {
            float s0 = 0.f, s1 = 0.f, s2 = 0.f, s3 = 0.f;
            #pragma unroll
            for (int i = 0; i < 16; ++i) {
                const int c = wv + 4 * i;
                bf16x4v hv = { (__bf16)v4[i].x, (__bf16)v4[i].y, (__bf16)v4[i].z, (__bf16)v4[i].w };
                *reinterpret_cast<bf16x4v*>(&tileh[c * THP + px4]) = hv;
                s0 += v4[i].x * v4[i].x; s1 += v4[i].y * v4[i].y;
                s2 += v4[i].z * v4[i].z; s3 += v4[i].w * v4[i].w;
            }
            sqpart[wv * SQP + px4    ] = s0; sqpart[wv * SQP + px4 + 1] = s1;
            sqpart[wv * SQP + px4 + 2] = s2; sqpart[wv * SQP + px4 + 3] = s3;
            lab_s[t] = labv;
        }
        bar_lds();
    }

    // ---- merge the 4 waves' K-split accumulators (native ds_add_f32), flush ----
    __syncthreads();
    #pragma unroll
    for (int r = 0; r < 16; ++r) {
        const int row = (r & 3) + 8 * (r >> 2) + 4 * h;   // C/D row = class
        unsafeAtomicAdd(&accf[row * GC + col], d0[r]);
        unsafeAtomicAdd(&accf[row * GC + col + 32], d1[r]);
    }
    __syncthreads();
    float* op = ws + (size_t)blockIdx.x * PST;
    for (int j = t; j < NCLS * GC; j += 256) op[j] = accf[j];   // [k][c_local]
}

// Per-pixel: sum the 4 group sq-partials, sqrt, segment-add norms+counts.
__global__ __launch_bounds__(256) void norm_kernel(
    const int* __restrict__ labels, float* __restrict__ ws)
{
    __shared__ float accN[NCLS], accC[NCLS];
    const int t = threadIdx.x;
    if (t < NCLS) { accN[t] = 0.f; accC[t] = 0.f; }
    __syncthreads();
    const float* sq = ws + OFF_SQ;
    const int p0 = blockIdx.x * (NPIX / NBLK);
    #pragma unroll
    for (int j = 0; j < NPIX / NBLK / 256; ++j) {
        const int p = p0 + j * 256 + t;
        const float s = sq[p] + sq[NPIX + p] + sq[2 * NPIX + p] + sq[3 * NPIX + p];
        const int k = labels[p];
        unsafeAtomicAdd(&accN[k], sqrtf(s));
        unsafeAtomicAdd(&accC[k], 1.f);
    }
    __syncthreads();
    if (t < NCLS) {
        ws[OFF_PN + (size_t)blockIdx.x * PNST + t] = accN[t];
        ws[OFF_PN + (size_t)blockIdx.x * PNST + 32 + t] = accC[t];
    }
}

// Final: 16 output slots per block; redundant count reduce; divide.
__global__ __launch_bounds__(256) void reduce_kernel(
    const float* __restrict__ ws, float* __restrict__ out)
{
    __shared__ float cred[NCLS][9];
    __shared__ float red[16][17];
    __shared__ float cnt_s[NCLS];
    const int t = threadIdx.x;

    if (t < NCLS * 8) {                      // counts: 19 x 8 lanes x 32 pnorm blocks
        const int k = t >> 3, gl = t & 7;
        float c = 0.f;
        #pragma unroll 8
        for (int j = 0; j < NBLK / 8; ++j)
            c += ws[OFF_PN + (size_t)(gl + 8 * j) * PNST + 32 + k];
        cred[k][gl] = c;
    }
    {
        const int ol = t & 15, gl = t >> 4;
        const int o = blockIdx.x * 16 + ol;
        float s = 0.f;
        if (o < SUMS) {                      // mean slot (k, c): 128 chunk-blocks of group c>>6
            const int k = o >> 8, c = o & 255, g = c >> 6, c6 = c & 63;
            #pragma unroll 4
            for (int j = 0; j < PCHUNKS / 16; ++j)
                s += ws[(size_t)((gl + 16 * j) * NGRP + g) * PST + k * GC + c6];
        } else if (o < PN_CNT) {             // norm slot k: 256 pnorm blocks
            const int k = o - SUMS;
            #pragma unroll 4
            for (int j = 0; j < NBLK / 16; ++j)
                s += ws[OFF_PN + (size_t)(gl + 16 * j) * PNST + k];
        }
        red[gl][ol] = s;
    }
    __syncthreads();
    if (t < NCLS) {
        float c = 0.f;
        #pragma unroll
        for (int g = 0; g < 8; ++g) c += cred[t][g];
        cnt_s[t] = c;
    }
    __syncthreads();
    if (t < 16) {
        const int oo = blockIdx.x * 16 + t;
        if (oo < PN_CNT) {
            float tot = 0.f;
            #pragma unroll
            for (int g = 0; g < 16; ++g) tot += red[g][t];
            const int k = (oo < SUMS) ? (oo >> 8) : (oo - SUMS);
            const float c = cnt_s[k];
            out[oo] = (c > 0.f) ? tot / fmaxf(c, 1.f) : 0.f;
        }
    }
}

extern "C" void kernel_launch(void* const* d_in, const int* in_sizes, int n_in,
                              void* d_out, int out_size, void* d_ws, size_t ws_size,
                              hipStream_t stream) {
    const float* feats  = (const float*)d_in[0];
    const int*   labels = (const int*)d_in[1];
    float* out = (float*)d_out;
    float* ws  = (float*)d_ws;   // partials 2.6MB | sqpix 4MB | pnorm 64KB

    accum_kernel<<<GRID, 256, 0, stream>>>(feats, labels, ws);
    norm_kernel<<<NBLK, 256, 0, stream>>>(labels, ws);
    reduce_kernel<<<(PN_CNT + 15) / 16, 256, 0, stream>>>(ws, out);
}